// Round 4
// baseline (92.260 us; speedup 1.0000x reference)
//
#include <hip/hip_runtime.h>
#include <hip/hip_cooperative_groups.h>
#include <math.h>

namespace cg = cooperative_groups;

#define PRE_LEN 64
#define BATCH   1024
#define NNB     256

// Math notes:
//   rotation preserves norm: x^2+y^2 = dx^2+dy^2 = r2
//   x^6+y^6 = r2*(r2^2 - 3*(x*y)^2),  x*y = dx*dy*cos(2a) - (dx^2-dy^2)*(ca*sa)
//   => per-neighbour precompute {nx, ny, cos(2a), ca*sa}; 17 VALU + 1 rsq per pair.
//   energy_i * cos(atan2(-dy,-dx)) = -60*dx / (den*sqrt(r2)); the final norm is
//   sign-invariant so we accumulate +s*dx, +s*dy.

__device__ __forceinline__ void field_block_partial(
    const float* __restrict__ output,
    const float* __restrict__ target,
    const float* __restrict__ nbr,
    float* __restrict__ ws,
    float4* s_nb, float (*s_ex)[64], float (*s_ey)[64],
    int b, int tid)
{
    if (tid < NNB) {
        const float* p = nbr + ((size_t)b * NNB + tid) * 5;
        const float nx  = p[0];
        const float ny  = p[1];
        const float ang = p[4];
        // v_sin/v_cos take revolutions: rev = (2*ang)/(2*pi) = ang/pi
        const float rev = ang * 0.31830988618f;
        const float c2  = __builtin_amdgcn_cosf(rev);   // cos(2a)
        const float s2  = __builtin_amdgcn_sinf(rev);   // sin(2a)
        s_nb[tid] = make_float4(nx, ny, c2, 0.5f * s2); // 0.5*sin(2a) = ca*sa
    }
    __syncthreads();

    const int t = tid & 63;
    const int q = tid >> 6;   // 0..7

    const size_t o_idx = (size_t)t * (BATCH * 2) + (size_t)b * 2;
    const float px = output[o_idx + 0];
    const float py = output[o_idx + 1];

    float ex = 0.0f, ey = 0.0f;
    const int n0 = q * 32;
#pragma unroll 4
    for (int i = 0; i < 32; ++i) {
        const float4 nb = s_nb[n0 + i];           // uniform addr -> broadcast
        const float dx  = px - nb.x;
        const float dy  = py - nb.y;
        const float dx2 = dx * dx;
        const float pp  = dx * dy;
        const float r2  = __builtin_fmaf(dy, dy, dx2);
        const float qq  = __builtin_fmaf(-dy, dy, dx2);   // dx^2 - dy^2
        const float t0  = qq * nb.w;
        const float xy  = __builtin_fmaf(pp, nb.z, -t0);  // x*y
        const float xy2 = xy * xy;
        const float r4  = r2 * r2;
        const float inr = __builtin_fmaf(xy2, -3.0f, r4); // r2^2 - 3*xy^2
        const float den = __builtin_fmaf(r2, inr, 6.0f);  // x^6+y^6+6
        const float m2  = den * den * r2;
        const float s   = 60.0f * __builtin_amdgcn_rsqf(m2);
        ex = __builtin_fmaf(s, dx, ex);
        ey = __builtin_fmaf(s, dy, ey);
    }

    s_ex[q][t] = ex;
    s_ey[q][t] = ey;
    __syncthreads();

    if (q == 0) {
        float tex = 0.0f, tey = 0.0f;
        #pragma unroll
        for (int k = 0; k < 8; ++k) { tex += s_ex[k][t]; tey += s_ey[k][t]; }
        const float en = sqrtf(tex * tex + tey * tey);

        const float tx = target[o_idx + 0];
        const float ty = target[o_idx + 1];
        const float ddx = px - tx, ddy = py - ty;

        float val = en * (1.0f / (PRE_LEN * BATCH))
                  + (ddx * ddx + ddy * ddy) * (1.0f / (PRE_LEN * BATCH * 2));

        #pragma unroll
        for (int off = 32; off > 0; off >>= 1)
            val += __shfl_down(val, off, 64);

        if (t == 0)
            ws[b] = val;
    }
}

// Fused cooperative version: grid.sync() then block 0 reduces the partials.
__global__ __launch_bounds__(512, 8) void field_loss_coop(
    const float* __restrict__ output,
    const float* __restrict__ target,
    const float* __restrict__ nbr,
    float* __restrict__ ws,
    float* __restrict__ out)
{
    __shared__ float4 s_nb[NNB];
    __shared__ float  s_ex[8][64], s_ey[8][64];

    const int b   = blockIdx.x;
    const int tid = threadIdx.x;

    field_block_partial(output, target, nbr, ws, s_nb, s_ex, s_ey, b, tid);

    cg::this_grid().sync();

    if (b == 0) {
        const int t = tid & 63;
        const int q = tid >> 6;
        float v = ws[tid] + ws[tid + 512];
        #pragma unroll
        for (int off = 32; off > 0; off >>= 1)
            v += __shfl_down(v, off, 64);
        if (t == 0) s_ex[0][q] = v;
        __syncthreads();
        if (tid == 0) {
            float r = 0.0f;
            #pragma unroll
            for (int k = 0; k < 8; ++k) r += s_ex[0][k];
            out[0] = r;
        }
    }
}

// Fallback (non-cooperative) pair, identical math.
__global__ __launch_bounds__(512, 8) void field_loss_stage1(
    const float* __restrict__ output,
    const float* __restrict__ target,
    const float* __restrict__ nbr,
    float* __restrict__ ws)
{
    __shared__ float4 s_nb[NNB];
    __shared__ float  s_ex[8][64], s_ey[8][64];
    field_block_partial(output, target, nbr, ws, s_nb, s_ex, s_ey,
                        blockIdx.x, threadIdx.x);
}

__global__ __launch_bounds__(256) void reduce_kernel(
    const float* __restrict__ ws,
    float* __restrict__ out)
{
    __shared__ float s_part[4];
    const int tid = threadIdx.x;
    const int t   = tid & 63;
    const int q   = tid >> 6;

    float val = ws[tid] + ws[tid + 256] + ws[tid + 512] + ws[tid + 768];

    #pragma unroll
    for (int off = 32; off > 0; off >>= 1)
        val += __shfl_down(val, off, 64);

    if (t == 0) s_part[q] = val;
    __syncthreads();

    if (tid == 0)
        out[0] = s_part[0] + s_part[1] + s_part[2] + s_part[3];
}

extern "C" void kernel_launch(void* const* d_in, const int* in_sizes, int n_in,
                              void* d_out, int out_size, void* d_ws, size_t ws_size,
                              hipStream_t stream) {
    const float* output = (const float*)d_in[0];
    const float* target = (const float*)d_in[1];
    const float* nbr    = (const float*)d_in[2];
    float* out = (float*)d_out;
    float* ws  = (float*)d_ws;      // >= 1024 floats

    void* args[] = { (void*)&output, (void*)&target, (void*)&nbr,
                     (void*)&ws, (void*)&out };
    hipError_t err = hipLaunchCooperativeKernel(
        (const void*)field_loss_coop, dim3(BATCH), dim3(512), args, 0, stream);

    if (err != hipSuccess) {
        // graph capture or residency refused the cooperative launch:
        // use the proven two-kernel path (same math, same result).
        field_loss_stage1<<<dim3(BATCH), dim3(512), 0, stream>>>(output, target, nbr, ws);
        reduce_kernel<<<dim3(1), dim3(256), 0, stream>>>(ws, out);
    }
}

// Round 5
// 38.671 us; speedup vs baseline: 2.3858x; 2.3858x over previous
//
#include <hip/hip_runtime.h>
#include <math.h>

#define PRE_LEN 64
#define BATCH   1024
#define NNB     256

// Math notes (validated R4, absmax 0.0):
//   rotation preserves norm: x^2+y^2 = r2
//   x^6+y^6 = r2*(r2^2 - 3*(x*y)^2),  x*y = dx*dy*cos(2a) - (dx^2-dy^2)*(ca*sa)
//   energy_i/r = 60 * rsq(den^2 * r2);  final norm is sign-invariant.
//
// Single dispatch + 4-byte memset. Cross-block reduction via the CUB/rocPRIM
// "last block" pattern: store partial -> release-fence -> atomicAdd(ctr);
// the 1024th incrementer re-reads all partials with agent-scope loads
// (cross-XCD safe) and writes out[0]. No grid.sync (R4: ~70us), no second
// kernel dispatch (R3: ~7us of launch+latency).
__global__ __launch_bounds__(512, 8) void field_loss_fused(
    const float* __restrict__ output,   // [PRE_LEN][BATCH][2]
    const float* __restrict__ target,   // [PRE_LEN][BATCH][2]
    const float* __restrict__ nbr,      // [BATCH][NNB][5]
    float* __restrict__ ws,             // [BATCH] partials
    unsigned int* __restrict__ ctr,     // [1], zeroed by memset each call
    float* __restrict__ out)            // [1]
{
    __shared__ float4 s_nb[NNB];            // {nx, ny, cos(2a), ca*sa}
    __shared__ float  s_ex[8][64], s_ey[8][64];
    __shared__ unsigned int s_old;

    const int b   = blockIdx.x;
    const int tid = threadIdx.x;

    if (tid < NNB) {
        const float* p = nbr + ((size_t)b * NNB + tid) * 5;
        const float nx  = p[0];
        const float ny  = p[1];
        const float ang = p[4];
        const float rev = ang * 0.31830988618f;         // (2a) / (2*pi)
        const float c2  = __builtin_amdgcn_cosf(rev);   // cos(2a)
        const float s2  = __builtin_amdgcn_sinf(rev);   // sin(2a)
        s_nb[tid] = make_float4(nx, ny, c2, 0.5f * s2); // 0.5*sin(2a) = ca*sa
    }
    __syncthreads();

    const int t = tid & 63;
    const int q = tid >> 6;   // 0..7

    const size_t o_idx = (size_t)t * (BATCH * 2) + (size_t)b * 2;
    const float px = output[o_idx + 0];
    const float py = output[o_idx + 1];

    float ex = 0.0f, ey = 0.0f;
    const int n0 = q * 32;
#pragma unroll 8
    for (int i = 0; i < 32; ++i) {
        const float4 nb = s_nb[n0 + i];           // uniform addr -> broadcast
        const float dx  = px - nb.x;
        const float dy  = py - nb.y;
        const float dx2 = dx * dx;
        const float pp  = dx * dy;
        const float r2  = __builtin_fmaf(dy, dy, dx2);
        const float qq  = __builtin_fmaf(-dy, dy, dx2);   // dx^2 - dy^2
        const float t0  = qq * nb.w;
        const float xy  = __builtin_fmaf(pp, nb.z, -t0);  // x*y
        const float xy2 = xy * xy;
        const float r4  = r2 * r2;
        const float inr = __builtin_fmaf(xy2, -3.0f, r4); // r2^2 - 3*xy^2
        const float den = __builtin_fmaf(r2, inr, 6.0f);  // x^6+y^6+6 >= 6
        const float m2  = den * den * r2;
        const float s   = 60.0f * __builtin_amdgcn_rsqf(m2);
        ex = __builtin_fmaf(s, dx, ex);
        ey = __builtin_fmaf(s, dy, ey);
    }

    s_ex[q][t] = ex;
    s_ey[q][t] = ey;
    __syncthreads();

    if (q == 0) {
        float tex = 0.0f, tey = 0.0f;
        #pragma unroll
        for (int k = 0; k < 8; ++k) { tex += s_ex[k][t]; tey += s_ey[k][t]; }
        const float en = sqrtf(tex * tex + tey * tey);

        const float tx = target[o_idx + 0];
        const float ty = target[o_idx + 1];
        const float ddx = px - tx, ddy = py - ty;

        float val = en * (1.0f / (PRE_LEN * BATCH))
                  + (ddx * ddx + ddy * ddy) * (1.0f / (PRE_LEN * BATCH * 2));

        #pragma unroll
        for (int off = 32; off > 0; off >>= 1)
            val += __shfl_down(val, off, 64);

        if (t == 0) {
            // release-store the partial to device scope, then signal.
            __hip_atomic_store(&ws[b], val, __ATOMIC_RELEASE,
                               __HIP_MEMORY_SCOPE_AGENT);
            s_old = __hip_atomic_fetch_add(ctr, 1u, __ATOMIC_ACQ_REL,
                                           __HIP_MEMORY_SCOPE_AGENT);
        }
    }
    __syncthreads();

    if (s_old == BATCH - 1) {
        // last block to finish: all 1024 partials are globally visible.
        float v = __hip_atomic_load(&ws[tid], __ATOMIC_RELAXED,
                                    __HIP_MEMORY_SCOPE_AGENT)
                + __hip_atomic_load(&ws[tid + 512], __ATOMIC_RELAXED,
                                    __HIP_MEMORY_SCOPE_AGENT);
        #pragma unroll
        for (int off = 32; off > 0; off >>= 1)
            v += __shfl_down(v, off, 64);
        if (t == 0) s_ex[0][q] = v;
        __syncthreads();
        if (tid == 0) {
            float r = 0.0f;
            #pragma unroll
            for (int k = 0; k < 8; ++k) r += s_ex[0][k];
            out[0] = r;
        }
    }
}

extern "C" void kernel_launch(void* const* d_in, const int* in_sizes, int n_in,
                              void* d_out, int out_size, void* d_ws, size_t ws_size,
                              hipStream_t stream) {
    const float* output = (const float*)d_in[0];
    const float* target = (const float*)d_in[1];
    const float* nbr    = (const float*)d_in[2];
    float* out = (float*)d_out;
    float* ws  = (float*)d_ws;                              // 1024 partials
    unsigned int* ctr = (unsigned int*)((char*)d_ws + 4096); // counter after them

    hipMemsetAsync(ctr, 0, sizeof(unsigned int), stream);   // tiny fill, graph-safe
    field_loss_fused<<<dim3(BATCH), dim3(512), 0, stream>>>(
        output, target, nbr, ws, ctr, out);
}

// Round 6
// 15.651 us; speedup vs baseline: 5.8947x; 2.4708x over previous
//
#include <hip/hip_runtime.h>
#include <math.h>

#define PRE_LEN 64
#define BATCH   1024
#define NNB     256

// Math (validated R4/R5, absmax 0.0):
//   rotation preserves norm: x^2+y^2 = r2
//   x^6+y^6 = r2*(r2^2 - 3*(x*y)^2),  x*y = dx*dy*cos(2a) - (dx^2-dy^2)*(ca*sa)
//   energy_i/r = 60 * rsq(den^2 * r2);  final norm is sign-invariant.
//
// Structure (R6): 256 threads/block (4 waves), 64 loop iters/thread — doubles
// per-thread work to amortize the per-block fixed costs (staging latency,
// sincos, barriers, tail) that R1-R5 showed dominate over VALU issue time.
// 1024 blocks x 4 waves = 16 waves/CU (4/SIMD) — enough to hide latency
// (R5: full occupancy gave only 16% VALUBusy, so occupancy isn't binding).
// Reduction: proven two-dispatch split (R3); no same-address atomics (R2/R5).
__global__ __launch_bounds__(256, 4) void field_loss_stage1(
    const float* __restrict__ output,   // [PRE_LEN][BATCH][2]
    const float* __restrict__ target,   // [PRE_LEN][BATCH][2]
    const float* __restrict__ nbr,      // [BATCH][NNB][5]
    float* __restrict__ ws)             // [BATCH] partials
{
    __shared__ float4 s_nb[NNB];        // {nx, ny, cos(2a), ca*sa}
    __shared__ float2 s_red[4][64];

    const int b   = blockIdx.x;
    const int tid = threadIdx.x;
    const int t   = tid & 63;
    const int q   = tid >> 6;           // wave 0..3

    // Issue the (uncoalesced, 8KB-stride) output/target loads FIRST so their
    // HBM latency overlaps the nbr staging + sincos below. 8B-aligned float2.
    const size_t o_idx = (size_t)t * (BATCH * 2) + (size_t)b * 2;
    const float2 pxy = *reinterpret_cast<const float2*>(&output[o_idx]);
    const float2 txy = *reinterpret_cast<const float2*>(&target[o_idx]);

    {
        const float* p = nbr + ((size_t)b * NNB + tid) * 5;
        const float nx  = p[0];
        const float ny  = p[1];
        const float ang = p[4];
        const float rev = ang * 0.31830988618f;         // (2a)/(2*pi)
        const float c2  = __builtin_amdgcn_cosf(rev);   // cos(2a)
        const float s2  = __builtin_amdgcn_sinf(rev);   // sin(2a)
        s_nb[tid] = make_float4(nx, ny, c2, 0.5f * s2); // 0.5*sin(2a) = ca*sa
    }
    __syncthreads();

    const float px = pxy.x;
    const float py = pxy.y;

    float ex = 0.0f, ey = 0.0f;
    const int n0 = q * 64;
#pragma unroll 8
    for (int i = 0; i < 64; ++i) {
        const float4 nb = s_nb[n0 + i];           // uniform addr -> broadcast
        const float dx  = px - nb.x;
        const float dy  = py - nb.y;
        const float dx2 = dx * dx;
        const float pp  = dx * dy;
        const float r2  = __builtin_fmaf(dy, dy, dx2);
        const float qq  = __builtin_fmaf(-dy, dy, dx2);   // dx^2 - dy^2
        const float t0  = qq * nb.w;
        const float xy  = __builtin_fmaf(pp, nb.z, -t0);  // x*y
        const float xy2 = xy * xy;
        const float r4  = r2 * r2;
        const float inr = __builtin_fmaf(xy2, -3.0f, r4); // r2^2 - 3*xy^2
        const float den = __builtin_fmaf(r2, inr, 6.0f);  // x^6+y^6+6 >= 6
        const float m2  = den * den * r2;
        const float s   = 60.0f * __builtin_amdgcn_rsqf(m2);
        ex = __builtin_fmaf(s, dx, ex);
        ey = __builtin_fmaf(s, dy, ey);
    }

    s_red[q][t] = make_float2(ex, ey);
    __syncthreads();

    if (q == 0) {
        float tex = 0.0f, tey = 0.0f;
        #pragma unroll
        for (int k = 0; k < 4; ++k) {
            const float2 r = s_red[k][t];
            tex += r.x; tey += r.y;
        }
        const float h2 = __builtin_fmaf(tex, tex, tey * tey);
        const float en = __builtin_amdgcn_sqrtf(h2);

        const float ddx = px - txy.x, ddy = py - txy.y;
        float val = en * (1.0f / (PRE_LEN * BATCH))
                  + (ddx * ddx + ddy * ddy) * (1.0f / (PRE_LEN * BATCH * 2));

        #pragma unroll
        for (int off = 32; off > 0; off >>= 1)
            val += __shfl_down(val, off, 64);

        if (t == 0)
            ws[b] = val;            // plain store, one per block
    }
}

// Stage 2: single 256-thread block reduces 1024 partials -> out[0].
__global__ __launch_bounds__(256) void reduce_kernel(
    const float* __restrict__ ws,   // [BATCH]
    float* __restrict__ out)        // [1]
{
    __shared__ float s_part[4];
    const int tid = threadIdx.x;
    const int t   = tid & 63;
    const int q   = tid >> 6;

    float val = ws[tid] + ws[tid + 256] + ws[tid + 512] + ws[tid + 768];

    #pragma unroll
    for (int off = 32; off > 0; off >>= 1)
        val += __shfl_down(val, off, 64);

    if (t == 0) s_part[q] = val;
    __syncthreads();

    if (tid == 0)
        out[0] = s_part[0] + s_part[1] + s_part[2] + s_part[3];
}

extern "C" void kernel_launch(void* const* d_in, const int* in_sizes, int n_in,
                              void* d_out, int out_size, void* d_ws, size_t ws_size,
                              hipStream_t stream) {
    const float* output = (const float*)d_in[0];
    const float* target = (const float*)d_in[1];
    const float* nbr    = (const float*)d_in[2];
    float* out = (float*)d_out;
    float* ws  = (float*)d_ws;      // >= 1024 floats

    field_loss_stage1<<<dim3(BATCH), dim3(256), 0, stream>>>(output, target, nbr, ws);
    reduce_kernel<<<dim3(1), dim3(256), 0, stream>>>(ws, out);
}